// Round 6
// baseline (442.086 us; speedup 1.0000x reference)
//
#include <hip/hip_runtime.h>
#include <hip/hip_bf16.h>

// MSACMixer: B=8, S=4096, D=1024
// out = ((softmax(x@wg^T) . {conv3,conv5,conv7}(val)) * sigmoid(gate)) @ w_down^T
// where [gate,val] = x @ w_up^T
//
// R5: persistent tile-loop GEMM — each block owns NTILES output tiles (same bm, bn sweeps),
//     K-phase ledger runs uninterrupted across tile boundaries (staging indexes a global
//     K-tile counter), epilogues overlap in-flight staging. 256 blocks, 1/CU.

#define MB 8
#define SS 4096
#define DD 1024
#define MM (MB * SS)   // 32768 rows
#define KD 1024
#define WSTR (256 * KD)

typedef __attribute__((ext_vector_type(8))) short short8;
typedef __attribute__((ext_vector_type(4))) float f32x4;

static __device__ __forceinline__ unsigned short f2bf(float f) {
    union { float f; unsigned u; } a; a.f = f;
    unsigned u = a.u;
    unsigned r = (u + 0x7FFFu + ((u >> 16) & 1u)) >> 16;   // RNE
    return (unsigned short)r;
}
static __device__ __forceinline__ float bf2f(unsigned short b) {
    union { unsigned u; float f; } a; a.u = ((unsigned)b) << 16;
    return a.f;
}

// ---------------------------------------------------------------- merged weight prep
__global__ void prep_misc(const float* __restrict__ w_up, const float* __restrict__ w_down,
                          const float* __restrict__ w3, const float* __restrict__ w5,
                          const float* __restrict__ w7,
                          ushort4* __restrict__ wub, ushort4* __restrict__ wdb,
                          float* __restrict__ wt) {
    const int n1 = 2048 * 1024 / 4, n2 = 1024 * 1024 / 4;
    int i = blockIdx.x * 256 + threadIdx.x;
    if (i < n1) {
        float4 v = ((const float4*)w_up)[i];
        ushort4 o; o.x = f2bf(v.x); o.y = f2bf(v.y); o.z = f2bf(v.z); o.w = f2bf(v.w);
        wub[i] = o;
    } else if (i < n1 + n2) {
        int j = i - n1;
        float4 v = ((const float4*)w_down)[j];
        ushort4 o; o.x = f2bf(v.x); o.y = f2bf(v.y); o.z = f2bf(v.z); o.w = f2bf(v.w);
        wdb[j] = o;
    } else if (i < n1 + n2 + DD) {
        int d = i - n1 - n2;
        #pragma unroll
        for (int j = 0; j < 3; j++) wt[j * DD + d] = w3[d * 3 + j];
        #pragma unroll
        for (int j = 0; j < 5; j++) wt[(3 + j) * DD + d] = w5[d * 5 + j];
        #pragma unroll
        for (int j = 0; j < 7; j++) wt[(8 + j) * DD + d] = w7[d * 7 + j];
    }
}

// ---------------------------------------------------------------- softmax gate weights + x cvt
__global__ void scale_cvt(const float* __restrict__ x, const float* __restrict__ wg,
                          unsigned short* __restrict__ xb, float* __restrict__ sw, int M) {
    int gw = (int)((blockIdx.x * (size_t)blockDim.x + threadIdx.x) >> 6);
    int lane = threadIdx.x & 63;
    if (gw >= M) return;
    const float* xr = x + (size_t)gw * DD + lane * 16;
    float4 xv[4];
    #pragma unroll
    for (int q = 0; q < 4; q++) xv[q] = ((const float4*)xr)[q];

    float s0 = 0.f, s1 = 0.f, s2 = 0.f;
    #pragma unroll
    for (int q = 0; q < 4; q++) {
        float4 w0 = ((const float4*)(wg + lane * 16))[q];
        float4 w1 = ((const float4*)(wg + DD + lane * 16))[q];
        float4 w2 = ((const float4*)(wg + 2 * DD + lane * 16))[q];
        s0 += xv[q].x*w0.x + xv[q].y*w0.y + xv[q].z*w0.z + xv[q].w*w0.w;
        s1 += xv[q].x*w1.x + xv[q].y*w1.y + xv[q].z*w1.z + xv[q].w*w1.w;
        s2 += xv[q].x*w2.x + xv[q].y*w2.y + xv[q].z*w2.z + xv[q].w*w2.w;
    }

    short8 ob[2];
    #pragma unroll
    for (int q = 0; q < 4; q++) {
        ob[q >> 1][(q & 1) * 4 + 0] = (short)f2bf(xv[q].x);
        ob[q >> 1][(q & 1) * 4 + 1] = (short)f2bf(xv[q].y);
        ob[q >> 1][(q & 1) * 4 + 2] = (short)f2bf(xv[q].z);
        ob[q >> 1][(q & 1) * 4 + 3] = (short)f2bf(xv[q].w);
    }
    *(short8*)(xb + (size_t)gw * DD + lane * 16) = ob[0];
    *(short8*)(xb + (size_t)gw * DD + lane * 16 + 8) = ob[1];

    #pragma unroll
    for (int off = 32; off >= 1; off >>= 1) {
        s0 += __shfl_xor(s0, off);
        s1 += __shfl_xor(s1, off);
        s2 += __shfl_xor(s2, off);
    }
    if (lane == 0) {
        float mx = fmaxf(s0, fmaxf(s1, s2));
        float e0 = expf(s0 - mx), e1 = expf(s1 - mx), e2 = expf(s2 - mx);
        float inv = 1.f / (e0 + e1 + e2);
        sw[(size_t)gw * 3 + 0] = e0 * inv;
        sw[(size_t)gw * 3 + 1] = e1 * inv;
        sw[(size_t)gw * 3 + 2] = e2 * inv;
    }
}

// ---------------------------------------------------------------- persistent 256^2 8-phase GEMM
// Block b: XCD k8=b&7, jb=b>>3; bm=(jb>>1)+k8*16 (constant), bn(t)=(jb&1)*(NBN/2)+t.
// K-phase ledger identical to R2-R4 but with a GLOBAL K-tile counter g in [0, NTILES*16):
//   A addr(g) = Ablk + (g&15)*64 ; B addr(g) = Wb0 + (g>>4)*WSTR + (g&15)*64.
// LDS buffer parity = g&1 (uniform across tile boundaries). Epilogue per tile runs between
// the phase barriers; its stores pollute vmcnt (gfx9) which only over-waits — safe.
template <int EPI, int NBN, int NTILES>
__global__ __launch_bounds__(512, 2) void gemm8(
    const unsigned short* __restrict__ A,   // [M,1024]
    const unsigned short* __restrict__ W,   // [N,1024]
    unsigned short* __restrict__ og,
    unsigned short* __restrict__ ov,
    float* __restrict__ of)
{
    __shared__ __align__(16) char lds[131072];
    const int tid = threadIdx.x;
    const int wid = tid >> 6, lane = tid & 63;
    const int l15 = lane & 15, l4 = lane >> 4;
    const int wr = wid >> 2, wc = wid & 3;

    const int b = blockIdx.x;
    const int k8 = b & 7, jb = b >> 3;
    const int bm = (jb >> 1) + k8 * 16;
    const int bn0 = (jb & 1) * (NBN / 2);
    const int GMAX = NTILES * 16 - 1;

    const unsigned short* Ablk = A + (size_t)bm * 256 * KD;
    const unsigned short* Wb0  = W + (size_t)bn0 * WSTR;

    const int r0 = tid >> 2;
    const int cch8 = ((((tid & 3) ^ ((r0 >> 1) & 3))) << 3);
    const int dst0 = wid * 64 * 16;

    const int swz = ((l15 >> 1) & 3) << 4;
    int aoff[2][4], boff[4];
    #pragma unroll
    for (int mh = 0; mh < 2; mh++)
        #pragma unroll
        for (int m = 0; m < 4; m++)
            aoff[mh][m] = (wr * 128 + mh * 64 + m * 16 + l15) * 64 + ((l4 * 16) ^ swz);
    #pragma unroll
    for (int n = 0; n < 4; n++)
        boff[n] = (wc * 64 + n * 16 + l15) * 64 + ((l4 * 16) ^ swz);

    f32x4 acc[8][4];
    #pragma unroll
    for (int m = 0; m < 8; m++)
        #pragma unroll
        for (int n = 0; n < 4; n++) acc[m][n] = (f32x4)0.f;

#define LDSA(bu,h) (lds + (bu) * 32768 + (h) * 16384)
#define LDSB(bu,h) (lds + 65536 + (bu) * 32768 + (h) * 16384)
#define ADDRA(g) (Ablk + ((g) & 15) * 64)
#define ADDRB(g) (Wb0 + (size_t)((g) >> 4) * WSTR + ((g) & 15) * 64)

#define STAGE(gp, lb) do { \
    __builtin_amdgcn_global_load_lds( \
        (const __attribute__((address_space(1))) void*)((gp) + (size_t)r0 * KD + cch8), \
        (__attribute__((address_space(3))) void*)((lb) + dst0), 16, 0, 0); \
    __builtin_amdgcn_global_load_lds( \
        (const __attribute__((address_space(1))) void*)((gp) + (size_t)(r0 + 128) * KD + cch8), \
        (__attribute__((address_space(3))) void*)((lb) + 8192 + dst0), 16, 0, 0); \
  } while (0)

    // prologue: g=0 kh0/kh1, g=1 kh0
    STAGE(ADDRA(0), LDSA(0,0));
    STAGE(ADDRB(0), LDSB(0,0));
    STAGE(ADDRA(0) + 32, LDSA(0,1));
    STAGE(ADDRB(0) + 32, LDSB(0,1));
    STAGE(ADDRA(1), LDSA(1,0));
    STAGE(ADDRB(1), LDSB(1,0));
    asm volatile("s_waitcnt vmcnt(8)" ::: "memory");
    __builtin_amdgcn_s_barrier();

    short8 bf0, bf1, bf2, bf3;

#define MFMA16(mh) do { \
    __builtin_amdgcn_s_setprio(1); \
    acc[(mh)*4+0][0] = __builtin_amdgcn_mfma_f32_16x16x32_bf16(af0, bf0, acc[(mh)*4+0][0], 0, 0, 0); \
    acc[(mh)*4+0][1] = __builtin_amdgcn_mfma_f32_16x16x32_bf16(af0, bf1, acc[(mh)*4+0][1], 0, 0, 0); \
    acc[(mh)*4+0][2] = __builtin_amdgcn_mfma_f32_16x16x32_bf16(af0, bf2, acc[(mh)*4+0][2], 0, 0, 0); \
    acc[(mh)*4+0][3] = __builtin_amdgcn_mfma_f32_16x16x32_bf16(af0, bf3, acc[(mh)*4+0][3], 0, 0, 0); \
    acc[(mh)*4+1][0] = __builtin_amdgcn_mfma_f32_16x16x32_bf16(af1, bf0, acc[(mh)*4+1][0], 0, 0, 0); \
    acc[(mh)*4+1][1] = __builtin_amdgcn_mfma_f32_16x16x32_bf16(af1, bf1, acc[(mh)*4+1][1], 0, 0, 0); \
    acc[(mh)*4+1][2] = __builtin_amdgcn_mfma_f32_16x16x32_bf16(af1, bf2, acc[(mh)*4+1][2], 0, 0, 0); \
    acc[(mh)*4+1][3] = __builtin_amdgcn_mfma_f32_16x16x32_bf16(af1, bf3, acc[(mh)*4+1][3], 0, 0, 0); \
    acc[(mh)*4+2][0] = __builtin_amdgcn_mfma_f32_16x16x32_bf16(af2, bf0, acc[(mh)*4+2][0], 0, 0, 0); \
    acc[(mh)*4+2][1] = __builtin_amdgcn_mfma_f32_16x16x32_bf16(af2, bf1, acc[(mh)*4+2][1], 0, 0, 0); \
    acc[(mh)*4+2][2] = __builtin_amdgcn_mfma_f32_16x16x32_bf16(af2, bf2, acc[(mh)*4+2][2], 0, 0, 0); \
    acc[(mh)*4+2][3] = __builtin_amdgcn_mfma_f32_16x16x32_bf16(af2, bf3, acc[(mh)*4+2][3], 0, 0, 0); \
    acc[(mh)*4+3][0] = __builtin_amdgcn_mfma_f32_16x16x32_bf16(af3, bf0, acc[(mh)*4+3][0], 0, 0, 0); \
    acc[(mh)*4+3][1] = __builtin_amdgcn_mfma_f32_16x16x32_bf16(af3, bf1, acc[(mh)*4+3][1], 0, 0, 0); \
    acc[(mh)*4+3][2] = __builtin_amdgcn_mfma_f32_16x16x32_bf16(af3, bf2, acc[(mh)*4+3][2], 0, 0, 0); \
    acc[(mh)*4+3][3] = __builtin_amdgcn_mfma_f32_16x16x32_bf16(af3, bf3, acc[(mh)*4+3][3], 0, 0, 0); \
    __builtin_amdgcn_s_setprio(0); \
  } while (0)

#define PHASE(rb, kk, mh, LB, sp, slb, DV) do { \
    const char* ab = LDSA(rb, kk); \
    short8 af0 = *(const short8*)(ab + aoff[mh][0]); \
    short8 af1 = *(const short8*)(ab + aoff[mh][1]); \
    short8 af2 = *(const short8*)(ab + aoff[mh][2]); \
    short8 af3 = *(const short8*)(ab + aoff[mh][3]); \
    if (LB) { const char* bb = LDSB(rb, kk); \
        bf0 = *(const short8*)(bb + boff[0]); \
        bf1 = *(const short8*)(bb + boff[1]); \
        bf2 = *(const short8*)(bb + boff[2]); \
        bf3 = *(const short8*)(bb + boff[3]); } \
    STAGE(sp, slb); \
    __builtin_amdgcn_s_barrier(); \
    MFMA16(mh); \
    if (DV) asm volatile("s_waitcnt vmcnt(8)" ::: "memory"); \
    __builtin_amdgcn_s_barrier(); \
  } while (0)

    #pragma unroll 1
    for (int t = 0; t < NTILES; ++t) {
        #pragma unroll 1
        for (int i = 0; i < 8; ++i) {
            const int g0 = t * 16 + 2 * i;                  // even global K-tile
            const int g2 = (g0 + 2 <= GMAX) ? g0 + 2 : GMAX;
            const int g3 = (g0 + 3 <= GMAX) ? g0 + 3 : GMAX;
            const unsigned short* pA1h = ADDRA(g0 + 1) + 32;
            const unsigned short* pB1h = ADDRB(g0 + 1) + 32;
            const unsigned short* pA20 = ADDRA(g2);
            const unsigned short* pB20 = ADDRB(g2);
            const unsigned short* pA30 = ADDRA(g3);
            const unsigned short* pB30 = ADDRB(g3);
            PHASE(0, 0, 0, 1, pA1h,      LDSA(1,1), 0);
            PHASE(0, 0, 1, 0, pB1h,      LDSB(1,1), 1);
            PHASE(0, 1, 0, 1, pA20,      LDSA(0,0), 0);
            PHASE(0, 1, 1, 0, pB20,      LDSB(0,0), 1);
            PHASE(1, 0, 0, 1, pA20 + 32, LDSA(0,1), 0);
            PHASE(1, 0, 1, 0, pB20 + 32, LDSB(0,1), 1);
            PHASE(1, 1, 0, 1, pA30,      LDSA(1,0), 0);
            PHASE(1, 1, 1, 0, pB30,      LDSB(1,0), 1);
        }

        // ---- epilogue for tile t (LDS untouched; stores overlap in-flight staging) ----
        const int grow0 = bm * 256 + wr * 128;
        const int gcol0 = (bn0 + t) * 256 + wc * 64;
        if (EPI == 0) {
            #pragma unroll
            for (int m = 0; m < 8; m++) {
                #pragma unroll
                for (int n = 0; n < 4; n++) {
                    int gcol = gcol0 + n * 16 + l15;
                    bool isgate = gcol < 1024;              // uniform per block
                    unsigned short* dst = isgate ? og : ov;
                    int cc = isgate ? gcol : gcol - 1024;
                    #pragma unroll
                    for (int r = 0; r < 4; r++) {
                        int grow = grow0 + m * 16 + l4 * 4 + r;
                        float v = acc[m][n][r];
                        float o = isgate ? (1.f / (1.f + __expf(-v))) : v;
                        dst[(size_t)grow * 1024 + cc] = f2bf(o);
                    }
                }
            }
        } else {
            #pragma unroll
            for (int m = 0; m < 8; m++) {
                #pragma unroll
                for (int n = 0; n < 4; n++) {
                    int gcol = gcol0 + n * 16 + l15;
                    #pragma unroll
                    for (int r = 0; r < 4; r++) {
                        int grow = grow0 + m * 16 + l4 * 4 + r;
                        of[(size_t)grow * 1024 + gcol] = acc[m][n][r];
                    }
                }
            }
        }
        #pragma unroll
        for (int m = 0; m < 8; m++)
            #pragma unroll
            for (int n = 0; n < 4; n++) acc[m][n] = (f32x4)0.f;
    }
    asm volatile("s_waitcnt vmcnt(0)" ::: "memory");
#undef PHASE
#undef MFMA16
#undef STAGE
#undef ADDRA
#undef ADDRB
#undef LDSA
#undef LDSB
}

// ---------------------------------------------------------------- conv + softmax-mix + gate
__global__ __launch_bounds__(256) void conv_mix(
    const unsigned short* __restrict__ val,
    unsigned short* __restrict__ ga,      // gate in / A2 out (in place)
    const float* __restrict__ sw,
    const float* __restrict__ wt)         // transposed taps [15][DD]
{
    const int tid = threadIdx.x;
    const int dg = tid & 63, sr = tid >> 6;
    const int half = blockIdx.x & 1;
    const size_t mgrp = (size_t)(blockIdx.x >> 1);
    const size_t m = mgrp * 4 + sr;
    const int s = (int)(m & (SS - 1));
    const int d0 = half * 512 + dg * 8;

    const float* w3t = wt;
    const float* w5t = wt + 3 * DD;
    const float* w7t = wt + 8 * DD;

    float c3[8], c5[8], c7[8];
    #pragma unroll
    for (int i = 0; i < 8; i++) { c3[i] = 0.f; c5[i] = 0.f; c7[i] = 0.f; }

    #pragma unroll
    for (int j = 0; j < 7; j++) {
        int soff = s - 6 + j;
        float v[8];
        if (soff >= 0) {
            short8 r = *(const short8*)(val + (m - 6 + j) * (size_t)DD + d0);
            #pragma unroll
            for (int i = 0; i < 8; i++) v[i] = bf2f((unsigned short)r[i]);
        } else {
            #pragma unroll
            for (int i = 0; i < 8; i++) v[i] = 0.f;
        }
        {
            const float4* p = (const float4*)(w7t + (size_t)j * DD + d0);
            float4 wa = p[0], wb = p[1];
            c7[0] += v[0]*wa.x; c7[1] += v[1]*wa.y; c7[2] += v[2]*wa.z; c7[3] += v[3]*wa.w;
            c7[4] += v[4]*wb.x; c7[5] += v[5]*wb.y; c7[6] += v[6]*wb.z; c7[7] += v[7]*wb.w;
        }
        if (j >= 2) {
            const float4* p = (const float4*)(w5t + (size_t)(j - 2) * DD + d0);
            float4 wa = p[0], wb = p[1];
            c5[0] += v[0]*wa.x; c5[1] += v[1]*wa.y; c5[2] += v[2]*wa.z; c5[3] += v[3]*wa.w;
            c5[4] += v[4]*wb.x; c5[5] += v[5]*wb.y; c5[6] += v[6]*wb.z; c5[7] += v[7]*wb.w;
        }
        if (j >= 4) {
            const float4* p = (const float4*)(w3t + (size_t)(j - 4) * DD + d0);
            float4 wa = p[0], wb = p[1];
            c3[0] += v[0]*wa.x; c3[1] += v[1]*wa.y; c3[2] += v[2]*wa.z; c3[3] += v[3]*wa.w;
            c3[4] += v[4]*wb.x; c3[5] += v[5]*wb.y; c3[6] += v[6]*wb.z; c3[7] += v[7]*wb.w;
        }
    }

    float s0 = sw[m * 3 + 0], s1 = sw[m * 3 + 1], s2 = sw[m * 3 + 2];
    short8 g = *(const short8*)(ga + m * (size_t)DD + d0);
    short8 o;
    #pragma unroll
    for (int i = 0; i < 8; i++) {
        float fused = s0 * c3[i] + s1 * c5[i] + s2 * c7[i];
        o[i] = (short)f2bf(fused * bf2f((unsigned short)g[i]));
    }
    *(short8*)(ga + m * (size_t)DD + d0) = o;
}

// ---------------------------------------------------------------- launch
extern "C" void kernel_launch(void* const* d_in, const int* in_sizes, int n_in,
                              void* d_out, int out_size, void* d_ws, size_t ws_size,
                              hipStream_t stream) {
    const float* x      = (const float*)d_in[0];
    const float* w_up   = (const float*)d_in[1];
    const float* w_down = (const float*)d_in[2];
    const float* w_gate = (const float*)d_in[3];
    const float* w3     = (const float*)d_in[4];
    const float* w5     = (const float*)d_in[5];
    const float* w7     = (const float*)d_in[6];
    float* out = (float*)d_out;

    char* ws = (char*)d_ws;
    const size_t NX = (size_t)MM * DD;
    unsigned short* xb   = (unsigned short*)ws;                               // 64 MiB
    unsigned short* wub  = (unsigned short*)(ws + NX * 2);                    // 4 MiB
    unsigned short* wdb  = (unsigned short*)(ws + NX * 2 + 4194304);          // 2 MiB
    unsigned short* gate = (unsigned short*)(ws + NX * 2 + 6291456);          // 64 MiB (becomes A2)
    unsigned short* valb = (unsigned short*)(ws + NX * 2 + 6291456 + NX * 2); // 64 MiB
    float*          sw   = (float*)(ws + NX * 2 + 6291456 + NX * 4);          // 384 KiB
    float*          wt   = (float*)(ws + NX * 2 + 6291456 + NX * 4 + 393216); // 60 KiB

    prep_misc<<<(2048*1024/4 + 1024*1024/4 + DD + 255) / 256, 256, 0, stream>>>(
        w_up, w_down, w3, w5, w7, (ushort4*)wub, (ushort4*)wdb, wt);
    scale_cvt<<<MM / 4, 256, 0, stream>>>(x, w_gate, xb, sw, MM);
    gemm8<0, 8, 4><<<256, 512, 0, stream>>>(xb, wub, gate, valb, nullptr);
    conv_mix<<<MM / 4 * 2, 256, 0, stream>>>(valb, gate, sw, wt);
    gemm8<1, 4, 2><<<256, 512, 0, stream>>>(gate, wdb, nullptr, nullptr, out);
    (void)in_sizes; (void)n_in; (void)out_size; (void)ws_size;
}

// Round 7
// 435.419 us; speedup vs baseline: 1.0153x; 1.0153x over previous
//
#include <hip/hip_runtime.h>
#include <hip/hip_bf16.h>

// MSACMixer: B=8, S=4096, D=1024
// out = ((softmax(x@wg^T) . {conv3,conv5,conv7}(val)) * sigmoid(gate)) @ w_down^T
// where [gate,val] = x @ w_up^T
//
// R6: 16-wave (1024-thr) 256^2 GEMM, 4x4 wave grid, wave tile 64x64.
//     Phase = one kh (K=32): 8 ds_read_b128 + 2 global_load_lds (16KB units) +
//     16 MFMA + vmcnt(4) + ONE barrier. Stage distance 3 kh into the region
//     consumed last phase. R4 XCD map + verified LDS swizzle kept.

#define MB 8
#define SS 4096
#define DD 1024
#define MM (MB * SS)   // 32768 rows
#define KD 1024

typedef __attribute__((ext_vector_type(8))) short short8;
typedef __attribute__((ext_vector_type(4))) float f32x4;

static __device__ __forceinline__ unsigned short f2bf(float f) {
    union { float f; unsigned u; } a; a.f = f;
    unsigned u = a.u;
    unsigned r = (u + 0x7FFFu + ((u >> 16) & 1u)) >> 16;   // RNE
    return (unsigned short)r;
}
static __device__ __forceinline__ float bf2f(unsigned short b) {
    union { unsigned u; float f; } a; a.u = ((unsigned)b) << 16;
    return a.f;
}

// ---------------------------------------------------------------- merged weight prep
__global__ void prep_misc(const float* __restrict__ w_up, const float* __restrict__ w_down,
                          const float* __restrict__ w3, const float* __restrict__ w5,
                          const float* __restrict__ w7,
                          ushort4* __restrict__ wub, ushort4* __restrict__ wdb,
                          float* __restrict__ wt) {
    const int n1 = 2048 * 1024 / 4, n2 = 1024 * 1024 / 4;
    int i = blockIdx.x * 256 + threadIdx.x;
    if (i < n1) {
        float4 v = ((const float4*)w_up)[i];
        ushort4 o; o.x = f2bf(v.x); o.y = f2bf(v.y); o.z = f2bf(v.z); o.w = f2bf(v.w);
        wub[i] = o;
    } else if (i < n1 + n2) {
        int j = i - n1;
        float4 v = ((const float4*)w_down)[j];
        ushort4 o; o.x = f2bf(v.x); o.y = f2bf(v.y); o.z = f2bf(v.z); o.w = f2bf(v.w);
        wdb[j] = o;
    } else if (i < n1 + n2 + DD) {
        int d = i - n1 - n2;
        #pragma unroll
        for (int j = 0; j < 3; j++) wt[j * DD + d] = w3[d * 3 + j];
        #pragma unroll
        for (int j = 0; j < 5; j++) wt[(3 + j) * DD + d] = w5[d * 5 + j];
        #pragma unroll
        for (int j = 0; j < 7; j++) wt[(8 + j) * DD + d] = w7[d * 7 + j];
    }
}

// ---------------------------------------------------------------- softmax gate weights + x cvt
__global__ void scale_cvt(const float* __restrict__ x, const float* __restrict__ wg,
                          unsigned short* __restrict__ xb, float* __restrict__ sw, int M) {
    int gw = (int)((blockIdx.x * (size_t)blockDim.x + threadIdx.x) >> 6);
    int lane = threadIdx.x & 63;
    if (gw >= M) return;
    const float* xr = x + (size_t)gw * DD + lane * 16;
    float4 xv[4];
    #pragma unroll
    for (int q = 0; q < 4; q++) xv[q] = ((const float4*)xr)[q];

    float s0 = 0.f, s1 = 0.f, s2 = 0.f;
    #pragma unroll
    for (int q = 0; q < 4; q++) {
        float4 w0 = ((const float4*)(wg + lane * 16))[q];
        float4 w1 = ((const float4*)(wg + DD + lane * 16))[q];
        float4 w2 = ((const float4*)(wg + 2 * DD + lane * 16))[q];
        s0 += xv[q].x*w0.x + xv[q].y*w0.y + xv[q].z*w0.z + xv[q].w*w0.w;
        s1 += xv[q].x*w1.x + xv[q].y*w1.y + xv[q].z*w1.z + xv[q].w*w1.w;
        s2 += xv[q].x*w2.x + xv[q].y*w2.y + xv[q].z*w2.z + xv[q].w*w2.w;
    }

    short8 ob[2];
    #pragma unroll
    for (int q = 0; q < 4; q++) {
        ob[q >> 1][(q & 1) * 4 + 0] = (short)f2bf(xv[q].x);
        ob[q >> 1][(q & 1) * 4 + 1] = (short)f2bf(xv[q].y);
        ob[q >> 1][(q & 1) * 4 + 2] = (short)f2bf(xv[q].z);
        ob[q >> 1][(q & 1) * 4 + 3] = (short)f2bf(xv[q].w);
    }
    *(short8*)(xb + (size_t)gw * DD + lane * 16) = ob[0];
    *(short8*)(xb + (size_t)gw * DD + lane * 16 + 8) = ob[1];

    #pragma unroll
    for (int off = 32; off >= 1; off >>= 1) {
        s0 += __shfl_xor(s0, off);
        s1 += __shfl_xor(s1, off);
        s2 += __shfl_xor(s2, off);
    }
    if (lane == 0) {
        float mx = fmaxf(s0, fmaxf(s1, s2));
        float e0 = expf(s0 - mx), e1 = expf(s1 - mx), e2 = expf(s2 - mx);
        float inv = 1.f / (e0 + e1 + e2);
        sw[(size_t)gw * 3 + 0] = e0 * inv;
        sw[(size_t)gw * 3 + 1] = e1 * inv;
        sw[(size_t)gw * 3 + 2] = e2 * inv;
    }
}

// ---------------------------------------------------------------- 16-wave 256^2 GEMM
// LDS: A 4 regions of 16KB (kh: 256 rows x 32 cols bf16) + B 4 regions. Region(g) = g&3.
// Phase p: ds_read region p&3 (4 A-frags + 4 B-frags), stage kh p+3 (clamped) into region
// (p-1)&3 (consumed last phase -> free past the barrier), 16 MFMA, vmcnt(4), s_barrier.
// vmcnt(4): 3 stage-pairs outstanding max, oldest pair (kh p+1) forced to land.
template <int EPI, int NBN>
__global__ __launch_bounds__(1024, 4) void gemm16(
    const unsigned short* __restrict__ A,   // [M,1024]
    const unsigned short* __restrict__ W,   // [N,1024]
    unsigned short* __restrict__ og,
    unsigned short* __restrict__ ov,
    float* __restrict__ of)
{
    __shared__ __align__(16) char lds[131072];
    const int tid = threadIdx.x;
    const int wid = tid >> 6, lane = tid & 63;
    const int l15 = lane & 15, l4 = lane >> 4;
    const int wr = wid >> 2, wc = wid & 3;

    // R4 XCD map: k8 = XCD, bn sweeps inner within each XCD's 16 bm-panels
    const int flat = blockIdx.x + gridDim.x * blockIdx.y;
    const int k8 = flat & 7, j = flat >> 3;
    const int bn = j % NBN;
    const int bm = j / NBN + k8 * 16;

    const unsigned short* Ablk = A + (size_t)bm * 256 * KD;
    const unsigned short* Wblk = W + (size_t)bn * 256 * KD;

    // staging: 1024 threads x 16B = one 16KB kh unit. dest linear, source pre-swizzled.
    const int r0 = tid >> 2;                                  // row 0..255
    const int cch8 = (((tid & 3) ^ ((r0 >> 1) & 3)) << 3);    // swizzled col elem
    const int dst0 = tid * 16;

    // read offsets within a kh region (64B rows), XOR-swizzled (R3-verified)
    const int swz = ((l15 >> 1) & 3) << 4;
    const int aoff0 = (wr * 64 + l15) * 64 + ((l4 * 16) ^ swz);
    const int boff0 = (wc * 64 + l15) * 64 + ((l4 * 16) ^ swz);

    f32x4 acc[4][4];
    #pragma unroll
    for (int m = 0; m < 4; m++)
        #pragma unroll
        for (int n = 0; n < 4; n++) acc[m][n] = (f32x4)0.f;

#define LDSA(r) (lds + (r) * 16384)
#define LDSB(r) (lds + 65536 + (r) * 16384)
#define STAGE1(gp, lb) __builtin_amdgcn_global_load_lds( \
        (const __attribute__((address_space(1))) void*)((gp) + (size_t)r0 * KD + cch8), \
        (__attribute__((address_space(3))) void*)((lb) + dst0), 16, 0, 0)

    // prologue: kh 0,1,2 (src elem offset of kh g = g*32)
    STAGE1(Ablk +  0, LDSA(0)); STAGE1(Wblk +  0, LDSB(0));
    STAGE1(Ablk + 32, LDSA(1)); STAGE1(Wblk + 32, LDSB(1));
    STAGE1(Ablk + 64, LDSA(2)); STAGE1(Wblk + 64, LDSB(2));
    asm volatile("s_waitcnt vmcnt(4)" ::: "memory");   // kh0 landed (per-wave) -> barrier makes it global
    __builtin_amdgcn_s_barrier();

#define PHASE(q, soff) do { \
    const char* ar = LDSA(q); const char* br = LDSB(q); \
    short8 af0 = *(const short8*)(ar + aoff0); \
    short8 af1 = *(const short8*)(ar + aoff0 + 1024); \
    short8 af2 = *(const short8*)(ar + aoff0 + 2048); \
    short8 af3 = *(const short8*)(ar + aoff0 + 3072); \
    short8 bf0 = *(const short8*)(br + boff0); \
    short8 bf1 = *(const short8*)(br + boff0 + 1024); \
    short8 bf2 = *(const short8*)(br + boff0 + 2048); \
    short8 bf3 = *(const short8*)(br + boff0 + 3072); \
    STAGE1(Ablk + (soff), LDSA(((q) + 3) & 3)); \
    STAGE1(Wblk + (soff), LDSB(((q) + 3) & 3)); \
    __builtin_amdgcn_s_setprio(1); \
    acc[0][0] = __builtin_amdgcn_mfma_f32_16x16x32_bf16(af0, bf0, acc[0][0], 0, 0, 0); \
    acc[0][1] = __builtin_amdgcn_mfma_f32_16x16x32_bf16(af0, bf1, acc[0][1], 0, 0, 0); \
    acc[0][2] = __builtin_amdgcn_mfma_f32_16x16x32_bf16(af0, bf2, acc[0][2], 0, 0, 0); \
    acc[0][3] = __builtin_amdgcn_mfma_f32_16x16x32_bf16(af0, bf3, acc[0][3], 0, 0, 0); \
    acc[1][0] = __builtin_amdgcn_mfma_f32_16x16x32_bf16(af1, bf0, acc[1][0], 0, 0, 0); \
    acc[1][1] = __builtin_amdgcn_mfma_f32_16x16x32_bf16(af1, bf1, acc[1][1], 0, 0, 0); \
    acc[1][2] = __builtin_amdgcn_mfma_f32_16x16x32_bf16(af1, bf2, acc[1][2], 0, 0, 0); \
    acc[1][3] = __builtin_amdgcn_mfma_f32_16x16x32_bf16(af1, bf3, acc[1][3], 0, 0, 0); \
    acc[2][0] = __builtin_amdgcn_mfma_f32_16x16x32_bf16(af2, bf0, acc[2][0], 0, 0, 0); \
    acc[2][1] = __builtin_amdgcn_mfma_f32_16x16x32_bf16(af2, bf1, acc[2][1], 0, 0, 0); \
    acc[2][2] = __builtin_amdgcn_mfma_f32_16x16x32_bf16(af2, bf2, acc[2][2], 0, 0, 0); \
    acc[2][3] = __builtin_amdgcn_mfma_f32_16x16x32_bf16(af2, bf3, acc[2][3], 0, 0, 0); \
    acc[3][0] = __builtin_amdgcn_mfma_f32_16x16x32_bf16(af3, bf0, acc[3][0], 0, 0, 0); \
    acc[3][1] = __builtin_amdgcn_mfma_f32_16x16x32_bf16(af3, bf1, acc[3][1], 0, 0, 0); \
    acc[3][2] = __builtin_amdgcn_mfma_f32_16x16x32_bf16(af3, bf2, acc[3][2], 0, 0, 0); \
    acc[3][3] = __builtin_amdgcn_mfma_f32_16x16x32_bf16(af3, bf3, acc[3][3], 0, 0, 0); \
    __builtin_amdgcn_s_setprio(0); \
    asm volatile("s_waitcnt vmcnt(4)" ::: "memory"); \
    __builtin_amdgcn_s_barrier(); \
  } while (0)

    #pragma unroll 1
    for (int it = 0; it < 8; ++it) {
        const int p0 = it * 4;
        const int g0 = (p0 + 3 < 31 ? p0 + 3 : 31) * 32;   // stage src elem offsets (clamped)
        const int g1 = (p0 + 4 < 31 ? p0 + 4 : 31) * 32;
        const int g2 = (p0 + 5 < 31 ? p0 + 5 : 31) * 32;
        const int g3 = (p0 + 6 < 31 ? p0 + 6 : 31) * 32;
        PHASE(0, g0);
        PHASE(1, g1);
        PHASE(2, g2);
        PHASE(3, g3);
    }
    asm volatile("s_waitcnt vmcnt(0)" ::: "memory");

    const int grow0 = bm * 256 + wr * 64;
    const int gcol0 = bn * 256 + wc * 64;
    if (EPI == 0) {
        #pragma unroll
        for (int m = 0; m < 4; m++) {
            #pragma unroll
            for (int n = 0; n < 4; n++) {
                int gcol = gcol0 + n * 16 + l15;
                bool isgate = gcol < 1024;          // uniform per block
                unsigned short* dst = isgate ? og : ov;
                int cc = isgate ? gcol : gcol - 1024;
                #pragma unroll
                for (int r = 0; r < 4; r++) {
                    int grow = grow0 + m * 16 + l4 * 4 + r;
                    float v = acc[m][n][r];
                    float o = isgate ? (1.f / (1.f + __expf(-v))) : v;
                    dst[(size_t)grow * 1024 + cc] = f2bf(o);
                }
            }
        }
    } else {
        #pragma unroll
        for (int m = 0; m < 4; m++) {
            #pragma unroll
            for (int n = 0; n < 4; n++) {
                int gcol = gcol0 + n * 16 + l15;
                #pragma unroll
                for (int r = 0; r < 4; r++) {
                    int grow = grow0 + m * 16 + l4 * 4 + r;
                    of[(size_t)grow * 1024 + gcol] = acc[m][n][r];
                }
            }
        }
    }
#undef PHASE
#undef STAGE1
#undef LDSA
#undef LDSB
}

// ---------------------------------------------------------------- conv + softmax-mix + gate
__global__ __launch_bounds__(256) void conv_mix(
    const unsigned short* __restrict__ val,
    unsigned short* __restrict__ ga,      // gate in / A2 out (in place)
    const float* __restrict__ sw,
    const float* __restrict__ wt)         // transposed taps [15][DD]
{
    const int tid = threadIdx.x;
    const int dg = tid & 63, sr = tid >> 6;
    const int half = blockIdx.x & 1;
    const size_t mgrp = (size_t)(blockIdx.x >> 1);
    const size_t m = mgrp * 4 + sr;
    const int s = (int)(m & (SS - 1));
    const int d0 = half * 512 + dg * 8;

    const float* w3t = wt;
    const float* w5t = wt + 3 * DD;
    const float* w7t = wt + 8 * DD;

    float c3[8], c5[8], c7[8];
    #pragma unroll
    for (int i = 0; i < 8; i++) { c3[i] = 0.f; c5[i] = 0.f; c7[i] = 0.f; }

    #pragma unroll
    for (int j = 0; j < 7; j++) {
        int soff = s - 6 + j;
        float v[8];
        if (soff >= 0) {
            short8 r = *(const short8*)(val + (m - 6 + j) * (size_t)DD + d0);
            #pragma unroll
            for (int i = 0; i < 8; i++) v[i] = bf2f((unsigned short)r[i]);
        } else {
            #pragma unroll
            for (int i = 0; i < 8; i++) v[i] = 0.f;
        }
        {
            const float4* p = (const float4*)(w7t + (size_t)j * DD + d0);
            float4 wa = p[0], wb = p[1];
            c7[0] += v[0]*wa.x; c7[1] += v[1]*wa.y; c7[2] += v[2]*wa.z; c7[3] += v[3]*wa.w;
            c7[4] += v[4]*wb.x; c7[5] += v[5]*wb.y; c7[6] += v[6]*wb.z; c7[7] += v[7]*wb.w;
        }
        if (j >= 2) {
            const float4* p = (const float4*)(w5t + (size_t)(j - 2) * DD + d0);
            float4 wa = p[0], wb = p[1];
            c5[0] += v[0]*wa.x; c5[1] += v[1]*wa.y; c5[2] += v[2]*wa.z; c5[3] += v[3]*wa.w;
            c5[4] += v[4]*wb.x; c5[5] += v[5]*wb.y; c5[6] += v[6]*wb.z; c5[7] += v[7]*wb.w;
        }
        if (j >= 4) {
            const float4* p = (const float4*)(w3t + (size_t)(j - 4) * DD + d0);
            float4 wa = p[0], wb = p[1];
            c3[0] += v[0]*wa.x; c3[1] += v[1]*wa.y; c3[2] += v[2]*wa.z; c3[3] += v[3]*wa.w;
            c3[4] += v[4]*wb.x; c3[5] += v[5]*wb.y; c3[6] += v[6]*wb.z; c3[7] += v[7]*wb.w;
        }
    }

    float s0 = sw[m * 3 + 0], s1 = sw[m * 3 + 1], s2 = sw[m * 3 + 2];
    short8 g = *(const short8*)(ga + m * (size_t)DD + d0);
    short8 o;
    #pragma unroll
    for (int i = 0; i < 8; i++) {
        float fused = s0 * c3[i] + s1 * c5[i] + s2 * c7[i];
        o[i] = (short)f2bf(fused * bf2f((unsigned short)g[i]));
    }
    *(short8*)(ga + m * (size_t)DD + d0) = o;
}

// ---------------------------------------------------------------- launch
extern "C" void kernel_launch(void* const* d_in, const int* in_sizes, int n_in,
                              void* d_out, int out_size, void* d_ws, size_t ws_size,
                              hipStream_t stream) {
    const float* x      = (const float*)d_in[0];
    const float* w_up   = (const float*)d_in[1];
    const float* w_down = (const float*)d_in[2];
    const float* w_gate = (const float*)d_in[3];
    const float* w3     = (const float*)d_in[4];
    const float* w5     = (const float*)d_in[5];
    const float* w7     = (const float*)d_in[6];
    float* out = (float*)d_out;

    char* ws = (char*)d_ws;
    const size_t NX = (size_t)MM * DD;
    unsigned short* xb   = (unsigned short*)ws;                               // 64 MiB
    unsigned short* wub  = (unsigned short*)(ws + NX * 2);                    // 4 MiB
    unsigned short* wdb  = (unsigned short*)(ws + NX * 2 + 4194304);          // 2 MiB
    unsigned short* gate = (unsigned short*)(ws + NX * 2 + 6291456);          // 64 MiB (becomes A2)
    unsigned short* valb = (unsigned short*)(ws + NX * 2 + 6291456 + NX * 2); // 64 MiB
    float*          sw   = (float*)(ws + NX * 2 + 6291456 + NX * 4);          // 384 KiB
    float*          wt   = (float*)(ws + NX * 2 + 6291456 + NX * 4 + 393216); // 60 KiB

    prep_misc<<<(2048*1024/4 + 1024*1024/4 + DD + 255) / 256, 256, 0, stream>>>(
        w_up, w_down, w3, w5, w7, (ushort4*)wub, (ushort4*)wdb, wt);
    scale_cvt<<<MM / 4, 256, 0, stream>>>(x, w_gate, xb, sw, MM);
    gemm16<0, 8><<<dim3(MM / 256, 2048 / 256), 1024, 0, stream>>>(xb, wub, gate, valb, nullptr);
    conv_mix<<<MM / 4 * 2, 256, 0, stream>>>(valb, gate, sw, wt);
    gemm16<1, 4><<<dim3(MM / 256, 1024 / 256), 1024, 0, stream>>>(gate, wdb, nullptr, nullptr, out);
    (void)in_sizes; (void)n_in; (void)out_size; (void)ws_size;
}

// Round 8
// 352.425 us; speedup vs baseline: 1.2544x; 1.2355x over previous
//
#include <hip/hip_runtime.h>
#include <hip/hip_bf16.h>

// MSACMixer: B=8, S=4096, D=1024
// out = ((softmax(x@wg^T) . {conv3,conv5,conv7}(val)) * sigmoid(gate)) @ w_down^T
// where [gate,val] = x @ w_up^T
//
// R7: conv_mix rewritten with LDS row-staging (32 rows/block, 7x re-read -> 1.19x),
//     rolling 7-row register window, hoisted weights. GEMM kept from R6 (best variant).

#define MB 8
#define SS 4096
#define DD 1024
#define MM (MB * SS)   // 32768 rows
#define KD 1024
#define CR 32          // conv rows per block

typedef __attribute__((ext_vector_type(8))) short short8;
typedef __attribute__((ext_vector_type(4))) float f32x4;

static __device__ __forceinline__ unsigned short f2bf(float f) {
    union { float f; unsigned u; } a; a.f = f;
    unsigned u = a.u;
    unsigned r = (u + 0x7FFFu + ((u >> 16) & 1u)) >> 16;   // RNE
    return (unsigned short)r;
}
static __device__ __forceinline__ float bf2f(unsigned short b) {
    union { unsigned u; float f; } a; a.u = ((unsigned)b) << 16;
    return a.f;
}

// ---------------------------------------------------------------- merged weight prep
__global__ void prep_misc(const float* __restrict__ w_up, const float* __restrict__ w_down,
                          const float* __restrict__ w3, const float* __restrict__ w5,
                          const float* __restrict__ w7,
                          ushort4* __restrict__ wub, ushort4* __restrict__ wdb,
                          float* __restrict__ wt) {
    const int n1 = 2048 * 1024 / 4, n2 = 1024 * 1024 / 4;
    int i = blockIdx.x * 256 + threadIdx.x;
    if (i < n1) {
        float4 v = ((const float4*)w_up)[i];
        ushort4 o; o.x = f2bf(v.x); o.y = f2bf(v.y); o.z = f2bf(v.z); o.w = f2bf(v.w);
        wub[i] = o;
    } else if (i < n1 + n2) {
        int j = i - n1;
        float4 v = ((const float4*)w_down)[j];
        ushort4 o; o.x = f2bf(v.x); o.y = f2bf(v.y); o.z = f2bf(v.z); o.w = f2bf(v.w);
        wdb[j] = o;
    } else if (i < n1 + n2 + DD) {
        int d = i - n1 - n2;
        #pragma unroll
        for (int j = 0; j < 3; j++) wt[j * DD + d] = w3[d * 3 + j];
        #pragma unroll
        for (int j = 0; j < 5; j++) wt[(3 + j) * DD + d] = w5[d * 5 + j];
        #pragma unroll
        for (int j = 0; j < 7; j++) wt[(8 + j) * DD + d] = w7[d * 7 + j];
    }
}

// ---------------------------------------------------------------- softmax gate weights + x cvt
__global__ void scale_cvt(const float* __restrict__ x, const float* __restrict__ wg,
                          unsigned short* __restrict__ xb, float* __restrict__ sw, int M) {
    int gw = (int)((blockIdx.x * (size_t)blockDim.x + threadIdx.x) >> 6);
    int lane = threadIdx.x & 63;
    if (gw >= M) return;
    const float* xr = x + (size_t)gw * DD + lane * 16;
    float4 xv[4];
    #pragma unroll
    for (int q = 0; q < 4; q++) xv[q] = ((const float4*)xr)[q];

    float s0 = 0.f, s1 = 0.f, s2 = 0.f;
    #pragma unroll
    for (int q = 0; q < 4; q++) {
        float4 w0 = ((const float4*)(wg + lane * 16))[q];
        float4 w1 = ((const float4*)(wg + DD + lane * 16))[q];
        float4 w2 = ((const float4*)(wg + 2 * DD + lane * 16))[q];
        s0 += xv[q].x*w0.x + xv[q].y*w0.y + xv[q].z*w0.z + xv[q].w*w0.w;
        s1 += xv[q].x*w1.x + xv[q].y*w1.y + xv[q].z*w1.z + xv[q].w*w1.w;
        s2 += xv[q].x*w2.x + xv[q].y*w2.y + xv[q].z*w2.z + xv[q].w*w2.w;
    }

    short8 ob[2];
    #pragma unroll
    for (int q = 0; q < 4; q++) {
        ob[q >> 1][(q & 1) * 4 + 0] = (short)f2bf(xv[q].x);
        ob[q >> 1][(q & 1) * 4 + 1] = (short)f2bf(xv[q].y);
        ob[q >> 1][(q & 1) * 4 + 2] = (short)f2bf(xv[q].z);
        ob[q >> 1][(q & 1) * 4 + 3] = (short)f2bf(xv[q].w);
    }
    *(short8*)(xb + (size_t)gw * DD + lane * 16) = ob[0];
    *(short8*)(xb + (size_t)gw * DD + lane * 16 + 8) = ob[1];

    #pragma unroll
    for (int off = 32; off >= 1; off >>= 1) {
        s0 += __shfl_xor(s0, off);
        s1 += __shfl_xor(s1, off);
        s2 += __shfl_xor(s2, off);
    }
    if (lane == 0) {
        float mx = fmaxf(s0, fmaxf(s1, s2));
        float e0 = expf(s0 - mx), e1 = expf(s1 - mx), e2 = expf(s2 - mx);
        float inv = 1.f / (e0 + e1 + e2);
        sw[(size_t)gw * 3 + 0] = e0 * inv;
        sw[(size_t)gw * 3 + 1] = e1 * inv;
        sw[(size_t)gw * 3 + 2] = e2 * inv;
    }
}

// ---------------------------------------------------------------- 16-wave 256^2 GEMM (R6)
template <int EPI, int NBN>
__global__ __launch_bounds__(1024, 4) void gemm16(
    const unsigned short* __restrict__ A,   // [M,1024]
    const unsigned short* __restrict__ W,   // [N,1024]
    unsigned short* __restrict__ og,
    unsigned short* __restrict__ ov,
    float* __restrict__ of)
{
    __shared__ __align__(16) char lds[131072];
    const int tid = threadIdx.x;
    const int wid = tid >> 6, lane = tid & 63;
    const int l15 = lane & 15, l4 = lane >> 4;
    const int wr = wid >> 2, wc = wid & 3;

    const int flat = blockIdx.x + gridDim.x * blockIdx.y;
    const int k8 = flat & 7, j = flat >> 3;
    const int bn = j % NBN;
    const int bm = j / NBN + k8 * 16;

    const unsigned short* Ablk = A + (size_t)bm * 256 * KD;
    const unsigned short* Wblk = W + (size_t)bn * 256 * KD;

    const int r0 = tid >> 2;
    const int cch8 = (((tid & 3) ^ ((r0 >> 1) & 3)) << 3);
    const int dst0 = tid * 16;

    const int swz = ((l15 >> 1) & 3) << 4;
    const int aoff0 = (wr * 64 + l15) * 64 + ((l4 * 16) ^ swz);
    const int boff0 = (wc * 64 + l15) * 64 + ((l4 * 16) ^ swz);

    f32x4 acc[4][4];
    #pragma unroll
    for (int m = 0; m < 4; m++)
        #pragma unroll
        for (int n = 0; n < 4; n++) acc[m][n] = (f32x4)0.f;

#define LDSA(r) (lds + (r) * 16384)
#define LDSB(r) (lds + 65536 + (r) * 16384)
#define STAGE1(gp, lb) __builtin_amdgcn_global_load_lds( \
        (const __attribute__((address_space(1))) void*)((gp) + (size_t)r0 * KD + cch8), \
        (__attribute__((address_space(3))) void*)((lb) + dst0), 16, 0, 0)

    STAGE1(Ablk +  0, LDSA(0)); STAGE1(Wblk +  0, LDSB(0));
    STAGE1(Ablk + 32, LDSA(1)); STAGE1(Wblk + 32, LDSB(1));
    STAGE1(Ablk + 64, LDSA(2)); STAGE1(Wblk + 64, LDSB(2));
    asm volatile("s_waitcnt vmcnt(4)" ::: "memory");
    __builtin_amdgcn_s_barrier();

#define PHASE(q, soff) do { \
    const char* ar = LDSA(q); const char* br = LDSB(q); \
    short8 af0 = *(const short8*)(ar + aoff0); \
    short8 af1 = *(const short8*)(ar + aoff0 + 1024); \
    short8 af2 = *(const short8*)(ar + aoff0 + 2048); \
    short8 af3 = *(const short8*)(ar + aoff0 + 3072); \
    short8 bf0 = *(const short8*)(br + boff0); \
    short8 bf1 = *(const short8*)(br + boff0 + 1024); \
    short8 bf2 = *(const short8*)(br + boff0 + 2048); \
    short8 bf3 = *(const short8*)(br + boff0 + 3072); \
    STAGE1(Ablk + (soff), LDSA(((q) + 3) & 3)); \
    STAGE1(Wblk + (soff), LDSB(((q) + 3) & 3)); \
    __builtin_amdgcn_s_setprio(1); \
    acc[0][0] = __builtin_amdgcn_mfma_f32_16x16x32_bf16(af0, bf0, acc[0][0], 0, 0, 0); \
    acc[0][1] = __builtin_amdgcn_mfma_f32_16x16x32_bf16(af0, bf1, acc[0][1], 0, 0, 0); \
    acc[0][2] = __builtin_amdgcn_mfma_f32_16x16x32_bf16(af0, bf2, acc[0][2], 0, 0, 0); \
    acc[0][3] = __builtin_amdgcn_mfma_f32_16x16x32_bf16(af0, bf3, acc[0][3], 0, 0, 0); \
    acc[1][0] = __builtin_amdgcn_mfma_f32_16x16x32_bf16(af1, bf0, acc[1][0], 0, 0, 0); \
    acc[1][1] = __builtin_amdgcn_mfma_f32_16x16x32_bf16(af1, bf1, acc[1][1], 0, 0, 0); \
    acc[1][2] = __builtin_amdgcn_mfma_f32_16x16x32_bf16(af1, bf2, acc[1][2], 0, 0, 0); \
    acc[1][3] = __builtin_amdgcn_mfma_f32_16x16x32_bf16(af1, bf3, acc[1][3], 0, 0, 0); \
    acc[2][0] = __builtin_amdgcn_mfma_f32_16x16x32_bf16(af2, bf0, acc[2][0], 0, 0, 0); \
    acc[2][1] = __builtin_amdgcn_mfma_f32_16x16x32_bf16(af2, bf1, acc[2][1], 0, 0, 0); \
    acc[2][2] = __builtin_amdgcn_mfma_f32_16x16x32_bf16(af2, bf2, acc[2][2], 0, 0, 0); \
    acc[2][3] = __builtin_amdgcn_mfma_f32_16x16x32_bf16(af2, bf3, acc[2][3], 0, 0, 0); \
    acc[3][0] = __builtin_amdgcn_mfma_f32_16x16x32_bf16(af3, bf0, acc[3][0], 0, 0, 0); \
    acc[3][1] = __builtin_amdgcn_mfma_f32_16x16x32_bf16(af3, bf1, acc[3][1], 0, 0, 0); \
    acc[3][2] = __builtin_amdgcn_mfma_f32_16x16x32_bf16(af3, bf2, acc[3][2], 0, 0, 0); \
    acc[3][3] = __builtin_amdgcn_mfma_f32_16x16x32_bf16(af3, bf3, acc[3][3], 0, 0, 0); \
    __builtin_amdgcn_s_setprio(0); \
    asm volatile("s_waitcnt vmcnt(4)" ::: "memory"); \
    __builtin_amdgcn_s_barrier(); \
  } while (0)

    #pragma unroll 1
    for (int it = 0; it < 8; ++it) {
        const int p0 = it * 4;
        const int g0 = (p0 + 3 < 31 ? p0 + 3 : 31) * 32;
        const int g1 = (p0 + 4 < 31 ? p0 + 4 : 31) * 32;
        const int g2 = (p0 + 5 < 31 ? p0 + 5 : 31) * 32;
        const int g3 = (p0 + 6 < 31 ? p0 + 6 : 31) * 32;
        PHASE(0, g0);
        PHASE(1, g1);
        PHASE(2, g2);
        PHASE(3, g3);
    }
    asm volatile("s_waitcnt vmcnt(0)" ::: "memory");

    const int grow0 = bm * 256 + wr * 64;
    const int gcol0 = bn * 256 + wc * 64;
    if (EPI == 0) {
        #pragma unroll
        for (int m = 0; m < 4; m++) {
            #pragma unroll
            for (int n = 0; n < 4; n++) {
                int gcol = gcol0 + n * 16 + l15;
                bool isgate = gcol < 1024;
                unsigned short* dst = isgate ? og : ov;
                int cc = isgate ? gcol : gcol - 1024;
                #pragma unroll
                for (int r = 0; r < 4; r++) {
                    int grow = grow0 + m * 16 + l4 * 4 + r;
                    float v = acc[m][n][r];
                    float o = isgate ? (1.f / (1.f + __expf(-v))) : v;
                    dst[(size_t)grow * 1024 + cc] = f2bf(o);
                }
            }
        }
    } else {
        #pragma unroll
        for (int m = 0; m < 4; m++) {
            #pragma unroll
            for (int n = 0; n < 4; n++) {
                int gcol = gcol0 + n * 16 + l15;
                #pragma unroll
                for (int r = 0; r < 4; r++) {
                    int grow = grow0 + m * 16 + l4 * 4 + r;
                    of[(size_t)grow * 1024 + gcol] = acc[m][n][r];
                }
            }
        }
    }
#undef PHASE
#undef STAGE1
#undef LDSA
#undef LDSB
}

// ---------------------------------------------------------------- conv + softmax-mix + gate
// Block = 32 output rows x full D. Stage rows r0-6..r0+31 in LDS (76 KB) once.
// Thread: fixed 8-wide d-chunk (ch = tid&127), sweeps 16 rows (rg = tid>>7) with a
// rolling 7-row f32 window (compile-time ring indices). Weights hoisted to regs.
__global__ __launch_bounds__(256) void conv_mix(
    const unsigned short* __restrict__ val,
    unsigned short* __restrict__ ga,      // gate in / A2 out (in place)
    const float* __restrict__ sw,
    const float* __restrict__ wt)         // transposed taps [15][DD]: 0-2 w3, 3-7 w5, 8-14 w7
{
    __shared__ unsigned short vlds[(CR + 6) * DD];   // 76 KB
    const int tid = threadIdx.x;
    const size_t r0 = (size_t)blockIdx.x * CR;       // global row base
    const int sbase = (int)(r0 & (SS - 1));          // within-batch start row

    for (int idx = tid; idx < (CR + 6) * (DD / 8); idx += 256) {
        const int row = idx >> 7;          // 0..37
        const int chs = idx & 127;
        short8 v;
        if (sbase - 6 + row >= 0)
            v = *(const short8*)(val + (r0 - 6 + row) * (size_t)DD + chs * 8);
        else {
            #pragma unroll
            for (int i = 0; i < 8; i++) v[i] = 0;
        }
        *(short8*)(&vlds[row * DD + chs * 8]) = v;
    }
    __syncthreads();

    const int ch = tid & 127;              // d-chunk: d0 = ch*8
    const int rg = tid >> 7;               // rows rg*16 .. rg*16+15
    const int d0 = ch * 8;
    const int k0 = rg * 16;

    float fw[15][8];
    #pragma unroll
    for (int j = 0; j < 15; j++) {
        float4 a = *(const float4*)(wt + j * DD + d0);
        float4 b = *(const float4*)(wt + j * DD + d0 + 4);
        fw[j][0] = a.x; fw[j][1] = a.y; fw[j][2] = a.z; fw[j][3] = a.w;
        fw[j][4] = b.x; fw[j][5] = b.y; fw[j][6] = b.z; fw[j][7] = b.w;
    }

    // rolling window: local lds row (k+t) lives in slot (k+t)%7
    float fwin[7][8];
    #pragma unroll
    for (int jj = 0; jj < 6; jj++) {
        short8 v = *(const short8*)(&vlds[(k0 + jj) * DD + d0]);
        #pragma unroll
        for (int i = 0; i < 8; i++) fwin[jj][i] = bf2f((unsigned short)v[i]);
    }

    #pragma unroll
    for (int k = 0; k < 16; k++) {
        {
            short8 v = *(const short8*)(&vlds[(k0 + k + 6) * DD + d0]);
            #pragma unroll
            for (int i = 0; i < 8; i++) fwin[(k + 6) % 7][i] = bf2f((unsigned short)v[i]);
        }
        const size_t m = r0 + k0 + k;
        const float s0 = sw[m * 3 + 0], s1 = sw[m * 3 + 1], s2 = sw[m * 3 + 2];
        short8 g = *(const short8*)(ga + m * DD + d0);
        short8 o;
        #pragma unroll
        for (int i = 0; i < 8; i++) {
            float c7v = 0.f, c5v = 0.f, c3v = 0.f;
            #pragma unroll
            for (int t = 0; t < 7; t++) c7v += fwin[(k + t) % 7][i] * fw[8 + t][i];
            #pragma unroll
            for (int t = 0; t < 5; t++) c5v += fwin[(k + t + 2) % 7][i] * fw[3 + t][i];
            #pragma unroll
            for (int t = 0; t < 3; t++) c3v += fwin[(k + t + 4) % 7][i] * fw[t][i];
            float fused = s0 * c3v + s1 * c5v + s2 * c7v;
            o[i] = (short)f2bf(fused * bf2f((unsigned short)g[i]));
        }
        *(short8*)(ga + m * DD + d0) = o;
    }
}

// ---------------------------------------------------------------- launch
extern "C" void kernel_launch(void* const* d_in, const int* in_sizes, int n_in,
                              void* d_out, int out_size, void* d_ws, size_t ws_size,
                              hipStream_t stream) {
    const float* x      = (const float*)d_in[0];
    const float* w_up   = (const float*)d_in[1];
    const float* w_down = (const float*)d_in[2];
    const float* w_gate = (const float*)d_in[3];
    const float* w3     = (const float*)d_in[4];
    const float* w5     = (const float*)d_in[5];
    const float* w7     = (const float*)d_in[6];
    float* out = (float*)d_out;

    char* ws = (char*)d_ws;
    const size_t NX = (size_t)MM * DD;
    unsigned short* xb   = (unsigned short*)ws;                               // 64 MiB
    unsigned short* wub  = (unsigned short*)(ws + NX * 2);                    // 4 MiB
    unsigned short* wdb  = (unsigned short*)(ws + NX * 2 + 4194304);          // 2 MiB
    unsigned short* gate = (unsigned short*)(ws + NX * 2 + 6291456);          // 64 MiB (becomes A2)
    unsigned short* valb = (unsigned short*)(ws + NX * 2 + 6291456 + NX * 2); // 64 MiB
    float*          sw   = (float*)(ws + NX * 2 + 6291456 + NX * 4);          // 384 KiB
    float*          wt   = (float*)(ws + NX * 2 + 6291456 + NX * 4 + 393216); // 60 KiB

    prep_misc<<<(2048*1024/4 + 1024*1024/4 + DD + 255) / 256, 256, 0, stream>>>(
        w_up, w_down, w3, w5, w7, (ushort4*)wub, (ushort4*)wdb, wt);
    scale_cvt<<<MM / 4, 256, 0, stream>>>(x, w_gate, xb, sw, MM);
    gemm16<0, 8><<<dim3(MM / 256, 2048 / 256), 1024, 0, stream>>>(xb, wub, gate, valb, nullptr);
    conv_mix<<<MM / CR, 256, 0, stream>>>(valb, gate, sw, wt);
    gemm16<1, 4><<<dim3(MM / 256, 1024 / 256), 1024, 0, stream>>>(gate, wdb, nullptr, nullptr, out);
    (void)in_sizes; (void)n_in; (void)out_size; (void)ws_size;
}